// Round 16
// baseline (702.282 us; speedup 1.0000x reference)
//
#include <hip/hip_runtime.h>

#define G 128
#define N 32
#define H 128
#define L 6

typedef _Float16 half8 __attribute__((ext_vector_type(8)));
typedef float f32x4 __attribute__((ext_vector_type(4)));

union H8 { unsigned u[4]; half8 v; };

__device__ inline unsigned short f16_bits(_Float16 h) {
  union { _Float16 f; unsigned short u; } c; c.f = h; return c.u;
}

// pack fp32 -> (f16 hi) | (f16 lo)<<16, hi = rne(x), lo = rne(x - hi)
__device__ inline unsigned packf16(float x) {
  _Float16 hi = (_Float16)x;
  _Float16 lo = (_Float16)(x - (float)hi);
  return (unsigned)f16_bits(hi) | ((unsigned)f16_bits(lo) << 16);
}

// ---------------------------------------------------------------------------
// E1: P0 = emb_x @ W0 + b0, P1 = emb_x @ W1 + b1. grid=2.
// ---------------------------------------------------------------------------
__global__ __launch_bounds__(256) void k_emb_mm(
    const float* __restrict__ emb_x,
    const float* __restrict__ W0, const float* __restrict__ b0, float* __restrict__ P0,
    const float* __restrict__ W1, const float* __restrict__ b1, float* __restrict__ P1) {
  const float* W = blockIdx.x ? W1 : W0;
  const float* b = blockIdx.x ? b1 : b0;
  float*       P = blockIdx.x ? P1 : P0;
  __shared__ float embs_t[128 * 32];   // [k][i]
  int tid = threadIdx.x;
  {
    int i = tid & 31, k0 = (tid >> 5) * 16;
    const float* src = emb_x + i * 128 + k0;
#pragma unroll
    for (int m = 0; m < 16; m++) embs_t[(k0 + m) * 32 + i] = src[m];
  }
  __syncthreads();
  int i  = tid >> 3;
  int h0 = (tid & 7) * 16;
  float acc[16];
#pragma unroll
  for (int hh = 0; hh < 16; hh++) acc[hh] = b[h0 + hh];
  for (int k = 0; k < 128; k++) {
    float a = embs_t[k * 32 + i];
    const float4* wr = (const float4*)(W + k * 128 + h0);
    float4 w0 = wr[0], w1 = wr[1], w2 = wr[2], w3 = wr[3];
    acc[0]  += a * w0.x; acc[1]  += a * w0.y; acc[2]  += a * w0.z; acc[3]  += a * w0.w;
    acc[4]  += a * w1.x; acc[5]  += a * w1.y; acc[6]  += a * w1.z; acc[7]  += a * w1.w;
    acc[8]  += a * w2.x; acc[9]  += a * w2.y; acc[10] += a * w2.z; acc[11] += a * w2.w;
    acc[12] += a * w3.x; acc[13] += a * w3.y; acc[14] += a * w3.z; acc[15] += a * w3.w;
  }
  float4* dst = (float4*)(P + i * 128 + h0);
  dst[0] = make_float4(acc[0], acc[1], acc[2], acc[3]);
  dst[1] = make_float4(acc[4], acc[5], acc[6], acc[7]);
  dst[2] = make_float4(acc[8], acc[9], acc[10], acc[11]);
  dst[3] = make_float4(acc[12], acc[13], acc[14], acc[15]);
}

// ---------------------------------------------------------------------------
// E2: build X h-planar: Xp[g][h][i*32+j]. One WG per graph.
// ---------------------------------------------------------------------------
__global__ __launch_bounds__(256) void k_buildX(
    const int* __restrict__ x_idx, const int* __restrict__ tf_idx,
    const float* __restrict__ P0, const float* __restrict__ P1,
    const float* __restrict__ emb_tf, float* __restrict__ Xp) {
  int g = blockIdx.x, tid = threadIdx.x;
  __shared__ float x0t[128 * 32];
  __shared__ float x1t[128 * 32];
  __shared__ float etf[128 * 16];
  __shared__ int   tfs[1024];
  {
    int i = tid & 31, h0 = (tid >> 5) * 16;
    int r = x_idx[g * 32 + i];
    const float* s0 = P0 + r * 128 + h0;
    const float* s1 = P1 + r * 128 + h0;
#pragma unroll
    for (int m = 0; m < 16; m++) {
      x0t[(h0 + m) * 32 + i] = s0[m];
      x1t[(h0 + m) * 32 + i] = s1[m];
    }
  }
  {
    int t = tid & 15, h0 = (tid >> 4) * 8;
    const float* s = emb_tf + t * 128 + h0;
#pragma unroll
    for (int m = 0; m < 8; m++) etf[(h0 + m) * 16 + t] = s[m];
  }
  ((int4*)tfs)[tid] = ((const int4*)(tf_idx + (size_t)g * 1024))[tid];
  __syncthreads();
  int i = tid >> 3, j0 = (tid & 7) * 4;
  int t0 = tfs[i * 32 + j0 + 0], t1 = tfs[i * 32 + j0 + 1];
  int t2 = tfs[i * 32 + j0 + 2], t3 = tfs[i * 32 + j0 + 3];
  float* outg = Xp + ((size_t)g << 17);
  for (int h = 0; h < 128; h++) {
    float a = x0t[h * 32 + i];
    const float* x1r = x1t + h * 32;
    const float* er  = etf + h * 16;
    float4 v;
    v.x = a * x1r[j0 + 0] * er[t0];
    v.y = a * x1r[j0 + 1] * er[t1];
    v.z = a * x1r[j0 + 2] * er[t2];
    v.w = a * x1r[j0 + 3] * er[t3];
    *(float4*)(outg + h * 1024 + tid * 4) = v;
  }
}

// ---------------------------------------------------------------------------
// PW: pre-pack Wc as f16 hi/lo pair planes, transposed for fragment loads.
// ---------------------------------------------------------------------------
__global__ __launch_bounds__(256) void k_packW(
    const float* __restrict__ Wc, unsigned* __restrict__ Whi,
    unsigned* __restrict__ Wlo) {
  int o  = blockIdx.x * 256 + threadIdx.x;      // 0 .. 49151
  int kp = o & 63;
  int h  = (o >> 6) & 127;
  int l  = o >> 13;
  const float* Wl = Wc + (size_t)l * 16384;
  float a = Wl[(2 * kp) * 128 + h];
  float b = Wl[(2 * kp + 1) * 128 + h];
  unsigned pa = packf16(a), pb = packf16(b);
  Whi[o] = __builtin_amdgcn_perm(pb, pa, 0x05040100u);
  Wlo[o] = __builtin_amdgcn_perm(pb, pa, 0x07060302u);
}

// ---------------------------------------------------------------------------
// KCA v17 (ALL 6 conv layers in ONE launch): one WG per (g, i-octet),
// grid G*4, 256 thr, launch_bounds(256,2). KEY FACT: WG (g,oct)'s phase A
// reads X[all planes][p in oct*256..+255] and its phase C writes the SAME
// range -> layer l+1's input for this WG is exactly its own layer-l output.
// The 6 layers are slab-local; a __syncthreads() between layers (HIP
// block-level global visibility) is the only sync needed. Eliminates 5
// inter-launch gaps (~15us each, the measured 145us wall/dispatch delta).
// Also vs v16 (bits unchanged -> absmax 0):
//  - c8 code bytes hoisted to registers (constant across planes/rounds/
//    layers): 16 LDS byte-loads/plane eliminated.
//  - Yp row stride 34->33 (plane 268): deposit writes AND B-frag uint2
//    reads now <=2-way bank conflicts (2-way free) vs 4-way reads before.
// Phase A/B/C logic otherwise v16 verbatim. LDS 74.2KB -> 2 WGs/CU.
// ---------------------------------------------------------------------------
__global__ __launch_bounds__(256, 2) void k_conv_all(
    float* __restrict__ Xp,
    const unsigned* __restrict__ WhiB, const unsigned* __restrict__ WloB,
    const float* __restrict__ bcB, const float* __restrict__ gcB,
    const float* __restrict__ ccB,
    const int* __restrict__ ea_idx, const int* __restrict__ adj,
    const float* __restrict__ emb_ea, float* __restrict__ Pm) {
  int g = blockIdx.x >> 2, oct = blockIdx.x & 3;
  int tid = threadIdx.x;
  int lane = tid & 63, wv = tid >> 6;
  int x = lane & 15, quad = lane >> 4;

  __shared__ __align__(16) unsigned char u_raw[65536];
  // phase A: Xs[2][8192 words] (double buffer, 32KB each)
  // phase C: Yp packed Y pairs, [32 planes][268 words], row stride 33
  unsigned* Yp = (unsigned*)u_raw;
  __shared__ unsigned char c8[1024];
  __shared__ unsigned epk[128 * 18];   // packed f16 hi|lo edge values

  // ---- setup: A-codes + pre-packed edge table (once for all layers)
  {
    int4 ev = ((const int4*)(ea_idx + (size_t)g * 1024))[tid];
    int4 av = ((const int4*)(adj   + (size_t)g * 1024))[tid];
    uchar4 c;
    c.x = av.x ? (unsigned char)ev.x : (unsigned char)16;
    c.y = av.y ? (unsigned char)ev.y : (unsigned char)16;
    c.z = av.z ? (unsigned char)ev.z : (unsigned char)16;
    c.w = av.w ? (unsigned char)ev.w : (unsigned char)16;
    ((uchar4*)c8)[tid] = c;
  }
#pragma unroll
  for (int it = 0; it < 8; it++) {
    int idx = it * 256 + tid;
    int e = idx >> 7, h = idx & 127;
    epk[h * 18 + e] = packf16(emb_ea[e * 128 + h]);
  }
  if (tid < 128) epk[tid * 18 + 16] = 0u;   // packf16(0) == 0
  __syncthreads();

  // ---- hoist A-op code bytes (constant across planes/rounds/layers)
  unsigned char cod[2][4][2];
#pragma unroll
  for (int jt = 0; jt < 2; jt++)
#pragma unroll
    for (int n = 0; n < 4; n++) {
      int k = quad * 8 + n * 2;
      cod[jt][n][0] = c8[k * 32 + jt * 16 + x];
      cod[jt][n][1] = c8[(k + 1) * 32 + jt * 16 + x];
    }

  const float* Xg = Xp + ((size_t)g << 17) + oct * 256;
  int xi = x & 7;

  auto STAGE = [&](unsigned* Xsb, int c) {
    unsigned pk[8][4];
#pragma unroll
    for (int m = 0; m < 8; m++) {
      float4 v = *(const float4*)(Xg + (size_t)(c * 32 + wv * 8 + m) * 1024 + lane * 4);
      pk[m][0] = packf16(v.x); pk[m][1] = packf16(v.y);
      pk[m][2] = packf16(v.z); pk[m][3] = packf16(v.w);
    }
#pragma unroll
    for (int r = 0; r < 4; r++) {
      int p = 4 * lane + r;
      int sw = (p >> 2) & 7;
#pragma unroll
      for (int B2 = 0; B2 < 2; B2++) {
        int B = wv * 2 + B2;
        uint4 q4;
        q4.x = pk[B2 * 4 + 0][r]; q4.y = pk[B2 * 4 + 1][r];
        q4.z = pk[B2 * 4 + 2][r]; q4.w = pk[B2 * 4 + 3][r];
        *(uint4*)&Xsb[p * 32 + ((B ^ sw) << 2)] = q4;
      }
    }
  };

#pragma unroll 1
  for (int l = 0; l < L; l++) {
    const unsigned* Whi = WhiB + l * 8192;
    const unsigned* Wlo = WloB + l * 8192;
    const float* bcl = bcB + l * H;
    const float* gcl = gcB + l * H;
    const float* ccl = ccB + l * H;
    int pool = (l == L - 1);

    __syncthreads();   // prev layer's phase C global writes visible; Yp free

    // ---- phase A: mlp. acc[pt][hh]; p = wv*64+pt*16+x, h = hh*16+quad*4+r
    f32x4 acc[4][8];
#pragma unroll
    for (int hh = 0; hh < 8; hh++) {
      float4 b4 = *(const float4*)(bcl + hh * 16 + quad * 4);
      f32x4 bi; bi[0] = b4.x; bi[1] = b4.y; bi[2] = b4.z; bi[3] = b4.w;
#pragma unroll
      for (int pt = 0; pt < 4; pt++) acc[pt][hh] = bi;
    }

    STAGE((unsigned*)u_raw, 0);
    __syncthreads();
#pragma unroll
    for (int c = 0; c < 4; c++) {
      unsigned* Xcur = (unsigned*)(u_raw + ((c & 1) ? 32768 : 0));
      if (c < 3) STAGE((unsigned*)(u_raw + (((c + 1) & 1) ? 32768 : 0)), c + 1);
      H8 bh[4], bl[4];
#pragma unroll
      for (int pt = 0; pt < 4; pt++) {
        int p = wv * 64 + pt * 16 + x;
        int sw = (p >> 2) & 7;
#pragma unroll
        for (int n = 0; n < 4; n++) {
          int k = quad * 8 + n * 2;
          uint2 d = *(const uint2*)&Xcur[p * 32 + (((k >> 2) ^ sw) << 2) + (k & 3)];
          bh[pt].u[n] = __builtin_amdgcn_perm(d.y, d.x, 0x05040100u);
          bl[pt].u[n] = __builtin_amdgcn_perm(d.y, d.x, 0x07060302u);
        }
      }
#pragma unroll
      for (int hh = 0; hh < 8; hh++) {
        int hrow = hh * 16 + x;
        H8 ah, al;
        *(uint4*)&ah.u[0] = *(const uint4*)(Whi + (size_t)hrow * 64 + c * 16 + quad * 4);
        *(uint4*)&al.u[0] = *(const uint4*)(Wlo + (size_t)hrow * 64 + c * 16 + quad * 4);
#pragma unroll
        for (int pt = 0; pt < 4; pt++) {
          acc[pt][hh] = __builtin_amdgcn_mfma_f32_16x16x32_f16(ah.v, bh[pt].v, acc[pt][hh], 0, 0, 0);
          acc[pt][hh] = __builtin_amdgcn_mfma_f32_16x16x32_f16(ah.v, bl[pt].v, acc[pt][hh], 0, 0, 0);
          acc[pt][hh] = __builtin_amdgcn_mfma_f32_16x16x32_f16(al.v, bh[pt].v, acc[pt][hh], 0, 0, 0);
        }
      }
      if (c < 3) __syncthreads();
    }

    // ---- phase B: LN + relu in registers (acc := Y)
    {
      float gm[4], gr[4];
#pragma unroll
      for (int pt = 0; pt < 4; pt++) {
        float s = 0.f;
#pragma unroll
        for (int hh = 0; hh < 8; hh++)
#pragma unroll
          for (int r = 0; r < 4; r++) s += acc[pt][hh][r];
        s += __shfl_xor(s, 16);
        s += __shfl_xor(s, 32);
        float m = s * (1.f / 128.f);
        float qv = 0.f;
#pragma unroll
        for (int hh = 0; hh < 8; hh++)
#pragma unroll
          for (int r = 0; r < 4; r++) { float d = acc[pt][hh][r] - m; qv += d * d; }
        qv += __shfl_xor(qv, 16);
        qv += __shfl_xor(qv, 32);
        gm[pt] = m;
        gr[pt] = rsqrtf(qv * (1.f / 128.f) + 1e-5f);
      }
#pragma unroll
      for (int hh = 0; hh < 8; hh++) {
        float4 g4 = *(const float4*)(gcl + hh * 16 + quad * 4);
        float4 c4 = *(const float4*)(ccl + hh * 16 + quad * 4);
        float ga[4] = {g4.x, g4.y, g4.z, g4.w};
        float ca[4] = {c4.x, c4.y, c4.z, c4.w};
#pragma unroll
        for (int r = 0; r < 4; r++)
#pragma unroll
          for (int pt = 0; pt < 4; pt++)
            acc[pt][hh][r] = fmaxf((acc[pt][hh][r] - gm[pt]) * gr[pt] * ga[r] + ca[r], 0.f);
      }
    }

    // ---- phase C: 4 rounds x 32 planes; msg via MFMA. Yp row stride 33,
    // plane stride 268 (<=2-way banking both directions).
#pragma unroll
    for (int q = 0; q < 4; q++) {
      __syncthreads();   // Yp region free (Xs reads done / prev round done)
#pragma unroll
      for (int hq = 0; hq < 2; hq++) {
        int hh = q * 2 + hq;
#pragma unroll
        for (int pt = 0; pt < 4; pt++) {
          int qv = pt * 16 + x;
          int ii = wv * 2 + (qv >> 5);
          int kk = qv & 31;
#pragma unroll
          for (int r = 0; r < 4; r++)
            Yp[(hq * 16 + quad * 4 + r) * 268 + ii * 33 + kk] = packf16(acc[pt][hh][r]);
        }
      }
      __syncthreads();
#pragma unroll 1
      for (int pl = 0; pl < 8; pl++) {
        int hrel = wv * 8 + pl;
        int h = q * 32 + hrel;
        // B-op (Y) fragments: col i = x, k = quad*8 + n*2 (+1)
        H8 ybh, ybl;
#pragma unroll
        for (int n = 0; n < 4; n++) {
          uint2 d = *(const uint2*)&Yp[hrel * 268 + x * 33 + quad * 8 + n * 2];
          ybh.u[n] = __builtin_amdgcn_perm(d.y, d.x, 0x05040100u);
          ybl.u[n] = __builtin_amdgcn_perm(d.y, d.x, 0x07060302u);
        }
        float* xrow = Xp + (((size_t)(g * 128 + h)) << 10) + (oct * 8 + xi) * 32;
        float psum = 0.f;
#pragma unroll
        for (int jt = 0; jt < 2; jt++) {
          // A-op (edge^T) via hoisted codes + pre-packed epk
          H8 ah, al;
#pragma unroll
          for (int n = 0; n < 4; n++) {
            unsigned p0 = epk[h * 18 + cod[jt][n][0]];
            unsigned p1 = epk[h * 18 + cod[jt][n][1]];
            ah.u[n] = __builtin_amdgcn_perm(p1, p0, 0x05040100u);
            al.u[n] = __builtin_amdgcn_perm(p1, p0, 0x07060302u);
          }
          float4 xv = *(const float4*)(xrow + jt * 16 + quad * 4);
          f32x4 cfr; cfr[0] = xv.x; cfr[1] = xv.y; cfr[2] = xv.z; cfr[3] = xv.w;
          cfr = __builtin_amdgcn_mfma_f32_16x16x32_f16(ah.v, ybh.v, cfr, 0, 0, 0);
          cfr = __builtin_amdgcn_mfma_f32_16x16x32_f16(ah.v, ybl.v, cfr, 0, 0, 0);
          cfr = __builtin_amdgcn_mfma_f32_16x16x32_f16(al.v, ybh.v, cfr, 0, 0, 0);
          if (!pool) {
            if (x < 8) {
              float4 o; o.x = cfr[0]; o.y = cfr[1]; o.z = cfr[2]; o.w = cfr[3];
              *(float4*)(xrow + jt * 16 + quad * 4) = o;
            }
          } else {
            psum += cfr[0] + cfr[1] + cfr[2] + cfr[3];
          }
        }
        if (pool) {
          psum += __shfl_xor(psum, 16);
          psum += __shfl_xor(psum, 32);
          if (quad == 0 && x < 8)
            Pm[(size_t)g * 4096 + h * 32 + oct * 8 + x] = psum * 0.03125f;
        }
      }
    }
  }
}

// ---------------------------------------------------------------------------
// T v3: reads pooled means from Pm[g][h][i] (written by k_conv_all's final
// layer). -> @Wp+bp -> rowLN -> relu -> sum over i -> @Wq1+bq1 -> LN ->
// relu -> @Wq2+bq2.
// ---------------------------------------------------------------------------
__global__ __launch_bounds__(256) void k_tail(
    const float* __restrict__ Pm,
    const float* __restrict__ Wp, const float* __restrict__ bp,
    const float* __restrict__ gp, const float* __restrict__ cp,
    const float* __restrict__ Wq1, const float* __restrict__ bq1,
    const float* __restrict__ gq1, const float* __restrict__ cq1,
    const float* __restrict__ Wq2, const float* __restrict__ bq2,
    float* __restrict__ out) {
  int g = blockIdx.x, tid = threadIdx.x;
  __shared__ float xs_s[32 * 132];
  __shared__ float y_s[32 * 132];
  __shared__ float stat_m[1], stat_r[1];
  __shared__ float hg_s[128];
  __shared__ float q_s[128];
  __shared__ float redf[128];
  const float* Pg = Pm + (size_t)g * 4096;
  {
    int h = tid >> 1, i0 = (tid & 1) * 16;
    const float4* src = (const float4*)(Pg + h * 32 + i0);
    float4 v0 = src[0], v1 = src[1], v2 = src[2], v3 = src[3];
    xs_s[(i0 +  0) * 132 + h] = v0.x; xs_s[(i0 +  1) * 132 + h] = v0.y;
    xs_s[(i0 +  2) * 132 + h] = v0.z; xs_s[(i0 +  3) * 132 + h] = v0.w;
    xs_s[(i0 +  4) * 132 + h] = v1.x; xs_s[(i0 +  5) * 132 + h] = v1.y;
    xs_s[(i0 +  6) * 132 + h] = v1.z; xs_s[(i0 +  7) * 132 + h] = v1.w;
    xs_s[(i0 +  8) * 132 + h] = v2.x; xs_s[(i0 +  9) * 132 + h] = v2.y;
    xs_s[(i0 + 10) * 132 + h] = v2.z; xs_s[(i0 + 11) * 132 + h] = v2.w;
    xs_s[(i0 + 12) * 132 + h] = v3.x; xs_s[(i0 + 13) * 132 + h] = v3.y;
    xs_s[(i0 + 14) * 132 + h] = v3.z; xs_s[(i0 + 15) * 132 + h] = v3.w;
  }
  __syncthreads();
  int i_ = tid >> 3, h0 = (tid & 7) * 16;
  float acc[16];
#pragma unroll
  for (int hh = 0; hh < 16; hh++) acc[hh] = bp[h0 + hh];
  for (int k = 0; k < 128; k++) {
    float a = xs_s[i_ * 132 + k];
    const float4* wr = (const float4*)(Wp + k * 128 + h0);
    float4 w0 = wr[0], w1 = wr[1], w2 = wr[2], w3 = wr[3];
    acc[0]  += a * w0.x; acc[1]  += a * w0.y; acc[2]  += a * w0.z; acc[3]  += a * w0.w;
    acc[4]  += a * w1.x; acc[5]  += a * w1.y; acc[6]  += a * w1.z; acc[7]  += a * w1.w;
    acc[8]  += a * w2.x; acc[9]  += a * w2.y; acc[10] += a * w2.z; acc[11] += a * w2.w;
    acc[12] += a * w3.x; acc[13] += a * w3.y; acc[14] += a * w3.z; acc[15] += a * w3.w;
  }
  {
    float s = 0.f;
#pragma unroll
    for (int hh = 0; hh < 16; hh++) s += acc[hh];
    s += __shfl_xor(s, 1); s += __shfl_xor(s, 2); s += __shfl_xor(s, 4);
    float m = s * (1.f / 128.f);
    float qv = 0.f;
#pragma unroll
    for (int hh = 0; hh < 16; hh++) { float d = acc[hh] - m; qv += d * d; }
    qv += __shfl_xor(qv, 1); qv += __shfl_xor(qv, 2); qv += __shfl_xor(qv, 4);
    float r = rsqrtf(qv * (1.f / 128.f) + 1e-5f);
#pragma unroll
    for (int hh = 0; hh < 16; hh++) {
      int hc = h0 + hh;
      float v = (acc[hh] - m) * r * gp[hc] + cp[hc];
      y_s[i_ * 132 + hc] = fmaxf(v, 0.f);
    }
  }
  __syncthreads();
  if (tid < 128) {
    float s = 0.f;
#pragma unroll
    for (int ii = 0; ii < 32; ii++) s += y_s[ii * 132 + tid];
    hg_s[tid] = s;
  }
  __syncthreads();
  if (tid < 128) {
    float a = bq1[tid];
    for (int k = 0; k < 128; k++) a += hg_s[k] * Wq1[k * 128 + tid];
    q_s[tid] = a;
  }
  __syncthreads();
  if (tid < 64) {
    float a = q_s[tid], b = q_s[tid + 64];
    float s = a + b;
#pragma unroll
    for (int o = 1; o < 64; o <<= 1) s += __shfl_xor(s, o);
    float m = s * (1.f / 128.f);
    float d1 = a - m, d2 = b - m;
    float qq = d1 * d1 + d2 * d2;
#pragma unroll
    for (int o = 1; o < 64; o <<= 1) qq += __shfl_xor(qq, o);
    if (tid == 0) { stat_m[0] = m; stat_r[0] = rsqrtf(qq * (1.f / 128.f) + 1e-5f); }
  }
  __syncthreads();
  if (tid < 128) {
    float v = (q_s[tid] - stat_m[0]) * stat_r[0] * gq1[tid] + cq1[tid];
    v = fmaxf(v, 0.f);
    redf[tid] = v * Wq2[tid];
  }
  __syncthreads();
  if (tid < 64) {
    float s = redf[tid] + redf[tid + 64];
#pragma unroll
    for (int o = 1; o < 64; o <<= 1) s += __shfl_xor(s, o);
    if (tid == 0) out[g] = s + bq2[0];
  }
}

// ---------------------------------------------------------------------------
extern "C" void kernel_launch(void* const* d_in, const int* in_sizes, int n_in,
                              void* d_out, int out_size, void* d_ws, size_t ws_size,
                              hipStream_t stream) {
  const int*   x_idx  = (const int*)d_in[0];
  const int*   ea_idx = (const int*)d_in[1];
  const int*   tf_idx = (const int*)d_in[2];
  const int*   adj    = (const int*)d_in[3];
  const float* emb_x  = (const float*)d_in[4];
  const float* emb_ea = (const float*)d_in[5];
  const float* emb_tf = (const float*)d_in[6];
  const float* W0  = (const float*)d_in[7];
  const float* b0  = (const float*)d_in[8];
  const float* W1  = (const float*)d_in[9];
  const float* b1  = (const float*)d_in[10];
  const float* Wc  = (const float*)d_in[11];
  const float* bc  = (const float*)d_in[12];
  const float* gc  = (const float*)d_in[13];
  const float* cc  = (const float*)d_in[14];
  const float* Wp  = (const float*)d_in[15];
  const float* bp  = (const float*)d_in[16];
  const float* gp  = (const float*)d_in[17];
  const float* cp  = (const float*)d_in[18];
  const float* Wq1 = (const float*)d_in[19];
  const float* bq1 = (const float*)d_in[20];
  const float* gq1 = (const float*)d_in[21];
  const float* cq1 = (const float*)d_in[22];
  const float* Wq2 = (const float*)d_in[23];
  const float* bq2 = (const float*)d_in[24];
  float* out = (float*)d_out;

  float* ws = (float*)d_ws;
  float* Xp = ws;
  float* Pm = ws + (size_t)16777216;
  float* P0 = ws + (size_t)33554432;
  float* P1 = P0 + 4096;
  unsigned* Whi = (unsigned*)(ws + (size_t)33562624);  // 6*128*64 u32
  unsigned* Wlo = Whi + 49152;

  k_emb_mm<<<2, 256, 0, stream>>>(emb_x, W0, b0, P0, W1, b1, P1);
  k_packW<<<192, 256, 0, stream>>>(Wc, Whi, Wlo);
  k_buildX<<<G, 256, 0, stream>>>(x_idx, tf_idx, P0, P1, emb_tf, Xp);
  k_conv_all<<<G * 4, 256, 0, stream>>>(Xp, Whi, Wlo, bc, gc, cc,
                                        ea_idx, adj, emb_ea, Pm);
  k_tail<<<G, 256, 0, stream>>>(Pm, Wp, bp, gp, cp, Wq1, bq1, gq1, cq1, Wq2, bq2, out);
}

// Round 17
// 663.661 us; speedup vs baseline: 1.0582x; 1.0582x over previous
//
#include <hip/hip_runtime.h>

#define G 128
#define N 32
#define H 128
#define L 6

typedef _Float16 half8 __attribute__((ext_vector_type(8)));
typedef float f32x4 __attribute__((ext_vector_type(4)));

union H8 { unsigned u[4]; half8 v; };

__device__ inline unsigned short f16_bits(_Float16 h) {
  union { _Float16 f; unsigned short u; } c; c.f = h; return c.u;
}

// pack fp32 -> (f16 hi) | (f16 lo)<<16, hi = rne(x), lo = rne(x - hi)
__device__ inline unsigned packf16(float x) {
  _Float16 hi = (_Float16)x;
  _Float16 lo = (_Float16)(x - (float)hi);
  return (unsigned)f16_bits(hi) | ((unsigned)f16_bits(lo) << 16);
}

// ---------------------------------------------------------------------------
// E1: P0 = emb_x @ W0 + b0, P1 = emb_x @ W1 + b1. grid=2.
// ---------------------------------------------------------------------------
__global__ __launch_bounds__(256) void k_emb_mm(
    const float* __restrict__ emb_x,
    const float* __restrict__ W0, const float* __restrict__ b0, float* __restrict__ P0,
    const float* __restrict__ W1, const float* __restrict__ b1, float* __restrict__ P1) {
  const float* W = blockIdx.x ? W1 : W0;
  const float* b = blockIdx.x ? b1 : b0;
  float*       P = blockIdx.x ? P1 : P0;
  __shared__ float embs_t[128 * 32];   // [k][i]
  int tid = threadIdx.x;
  {
    int i = tid & 31, k0 = (tid >> 5) * 16;
    const float* src = emb_x + i * 128 + k0;
#pragma unroll
    for (int m = 0; m < 16; m++) embs_t[(k0 + m) * 32 + i] = src[m];
  }
  __syncthreads();
  int i  = tid >> 3;
  int h0 = (tid & 7) * 16;
  float acc[16];
#pragma unroll
  for (int hh = 0; hh < 16; hh++) acc[hh] = b[h0 + hh];
  for (int k = 0; k < 128; k++) {
    float a = embs_t[k * 32 + i];
    const float4* wr = (const float4*)(W + k * 128 + h0);
    float4 w0 = wr[0], w1 = wr[1], w2 = wr[2], w3 = wr[3];
    acc[0]  += a * w0.x; acc[1]  += a * w0.y; acc[2]  += a * w0.z; acc[3]  += a * w0.w;
    acc[4]  += a * w1.x; acc[5]  += a * w1.y; acc[6]  += a * w1.z; acc[7]  += a * w1.w;
    acc[8]  += a * w2.x; acc[9]  += a * w2.y; acc[10] += a * w2.z; acc[11] += a * w2.w;
    acc[12] += a * w3.x; acc[13] += a * w3.y; acc[14] += a * w3.z; acc[15] += a * w3.w;
  }
  float4* dst = (float4*)(P + i * 128 + h0);
  dst[0] = make_float4(acc[0], acc[1], acc[2], acc[3]);
  dst[1] = make_float4(acc[4], acc[5], acc[6], acc[7]);
  dst[2] = make_float4(acc[8], acc[9], acc[10], acc[11]);
  dst[3] = make_float4(acc[12], acc[13], acc[14], acc[15]);
}

// ---------------------------------------------------------------------------
// E2: build X h-planar: Xp[g][h][i*32+j]. One WG per graph.
// ---------------------------------------------------------------------------
__global__ __launch_bounds__(256) void k_buildX(
    const int* __restrict__ x_idx, const int* __restrict__ tf_idx,
    const float* __restrict__ P0, const float* __restrict__ P1,
    const float* __restrict__ emb_tf, float* __restrict__ Xp) {
  int g = blockIdx.x, tid = threadIdx.x;
  __shared__ float x0t[128 * 32];
  __shared__ float x1t[128 * 32];
  __shared__ float etf[128 * 16];
  __shared__ int   tfs[1024];
  {
    int i = tid & 31, h0 = (tid >> 5) * 16;
    int r = x_idx[g * 32 + i];
    const float* s0 = P0 + r * 128 + h0;
    const float* s1 = P1 + r * 128 + h0;
#pragma unroll
    for (int m = 0; m < 16; m++) {
      x0t[(h0 + m) * 32 + i] = s0[m];
      x1t[(h0 + m) * 32 + i] = s1[m];
    }
  }
  {
    int t = tid & 15, h0 = (tid >> 4) * 8;
    const float* s = emb_tf + t * 128 + h0;
#pragma unroll
    for (int m = 0; m < 8; m++) etf[(h0 + m) * 16 + t] = s[m];
  }
  ((int4*)tfs)[tid] = ((const int4*)(tf_idx + (size_t)g * 1024))[tid];
  __syncthreads();
  int i = tid >> 3, j0 = (tid & 7) * 4;
  int t0 = tfs[i * 32 + j0 + 0], t1 = tfs[i * 32 + j0 + 1];
  int t2 = tfs[i * 32 + j0 + 2], t3 = tfs[i * 32 + j0 + 3];
  float* outg = Xp + ((size_t)g << 17);
  for (int h = 0; h < 128; h++) {
    float a = x0t[h * 32 + i];
    const float* x1r = x1t + h * 32;
    const float* er  = etf + h * 16;
    float4 v;
    v.x = a * x1r[j0 + 0] * er[t0];
    v.y = a * x1r[j0 + 1] * er[t1];
    v.z = a * x1r[j0 + 2] * er[t2];
    v.w = a * x1r[j0 + 3] * er[t3];
    *(float4*)(outg + h * 1024 + tid * 4) = v;
  }
}

// ---------------------------------------------------------------------------
// PW: pre-pack Wc as f16 hi/lo pair planes, transposed for fragment loads.
// ---------------------------------------------------------------------------
__global__ __launch_bounds__(256) void k_packW(
    const float* __restrict__ Wc, unsigned* __restrict__ Whi,
    unsigned* __restrict__ Wlo) {
  int o  = blockIdx.x * 256 + threadIdx.x;      // 0 .. 49151
  int kp = o & 63;
  int h  = (o >> 6) & 127;
  int l  = o >> 13;
  const float* Wl = Wc + (size_t)l * 16384;
  float a = Wl[(2 * kp) * 128 + h];
  float b = Wl[(2 * kp + 1) * 128 + h];
  unsigned pa = packf16(a), pb = packf16(b);
  Whi[o] = __builtin_amdgcn_perm(pb, pa, 0x05040100u);
  Wlo[o] = __builtin_amdgcn_perm(pb, pa, 0x07060302u);
}

// ---------------------------------------------------------------------------
// KF v18 (fused conv layer): v16 (verified 60us/dispatch, total 529, absmax
// 0) + per-round RESIDUAL PREFETCH. v17's mono-kernel fusion regressed
// (L2 assumption wrong) and is reverted; its two verified-correct micro-opts
// are kept (cod[] hoist, Yp row stride 33 -> <=2-way LDS banking).
// Diagnosis: phase C's "#pragma unroll 1" plane loop serialized 32
// dependent global residual reads (~900cy each) per wave. Fix: per round,
// prefetch all 16 residual float4s (8 planes x 2 jt, +64 VGPRs - free:
// LDS 74KB pins us at 2 WGs/CU for any VGPR<=256) BEFORE the plane loop,
// then FULLY UNROLL the plane loop (static indexing, rule #20).
// grid G*4, 256 thr, launch_bounds(256,2). Bits unchanged -> absmax 0.
// Watch: WRITE_SIZE must stay ~65.5MB (jump => spill => revert to v16).
// ---------------------------------------------------------------------------
template <int POOL>
__global__ __launch_bounds__(256, 2) void k_fused(
    float* __restrict__ Xp,
    const unsigned* __restrict__ Whi, const unsigned* __restrict__ Wlo,
    const float* __restrict__ bcl, const float* __restrict__ gcl,
    const float* __restrict__ ccl,
    const int* __restrict__ ea_idx, const int* __restrict__ adj,
    const float* __restrict__ emb_ea, float* __restrict__ Pm) {
  int g = blockIdx.x >> 2, oct = blockIdx.x & 3;
  int tid = threadIdx.x;
  int lane = tid & 63, wv = tid >> 6;
  int x = lane & 15, quad = lane >> 4;

  __shared__ __align__(16) unsigned char u_raw[65536];
  // phase A: Xs[2][8192 words] (double buffer, 32KB each)
  // phase C: Yp packed Y pairs, [32 planes][268 words], row stride 33
  unsigned* Yp = (unsigned*)u_raw;
  __shared__ unsigned char c8[1024];
  __shared__ unsigned epk[128 * 18];   // packed f16 hi|lo edge values

  // ---- setup: A-codes + pre-packed edge table
  {
    int4 ev = ((const int4*)(ea_idx + (size_t)g * 1024))[tid];
    int4 av = ((const int4*)(adj   + (size_t)g * 1024))[tid];
    uchar4 c;
    c.x = av.x ? (unsigned char)ev.x : (unsigned char)16;
    c.y = av.y ? (unsigned char)ev.y : (unsigned char)16;
    c.z = av.z ? (unsigned char)ev.z : (unsigned char)16;
    c.w = av.w ? (unsigned char)ev.w : (unsigned char)16;
    ((uchar4*)c8)[tid] = c;
  }
#pragma unroll
  for (int it = 0; it < 8; it++) {
    int idx = it * 256 + tid;
    int e = idx >> 7, h = idx & 127;
    epk[h * 18 + e] = packf16(emb_ea[e * 128 + h]);
  }
  if (tid < 128) epk[tid * 18 + 16] = 0u;   // packf16(0) == 0
  __syncthreads();

  // ---- hoist A-op code bytes (constant across planes/rounds)
  unsigned char cod[2][4][2];
#pragma unroll
  for (int jt = 0; jt < 2; jt++)
#pragma unroll
    for (int n = 0; n < 4; n++) {
      int k = quad * 8 + n * 2;
      cod[jt][n][0] = c8[k * 32 + jt * 16 + x];
      cod[jt][n][1] = c8[(k + 1) * 32 + jt * 16 + x];
    }

  // ---- phase A: mlp. acc[pt][hh]; p = wv*64+pt*16+x, h = hh*16+quad*4+r
  f32x4 acc[4][8];
#pragma unroll
  for (int hh = 0; hh < 8; hh++) {
    float4 b4 = *(const float4*)(bcl + hh * 16 + quad * 4);
    f32x4 bi; bi[0] = b4.x; bi[1] = b4.y; bi[2] = b4.z; bi[3] = b4.w;
#pragma unroll
    for (int pt = 0; pt < 4; pt++) acc[pt][hh] = bi;
  }
  const float* Xg = Xp + ((size_t)g << 17) + oct * 256;

  auto STAGE = [&](unsigned* Xsb, int c) {
    unsigned pk[8][4];
#pragma unroll
    for (int m = 0; m < 8; m++) {
      float4 v = *(const float4*)(Xg + (size_t)(c * 32 + wv * 8 + m) * 1024 + lane * 4);
      pk[m][0] = packf16(v.x); pk[m][1] = packf16(v.y);
      pk[m][2] = packf16(v.z); pk[m][3] = packf16(v.w);
    }
#pragma unroll
    for (int r = 0; r < 4; r++) {
      int p = 4 * lane + r;
      int sw = (p >> 2) & 7;
#pragma unroll
      for (int B2 = 0; B2 < 2; B2++) {
        int B = wv * 2 + B2;
        uint4 q4;
        q4.x = pk[B2 * 4 + 0][r]; q4.y = pk[B2 * 4 + 1][r];
        q4.z = pk[B2 * 4 + 2][r]; q4.w = pk[B2 * 4 + 3][r];
        *(uint4*)&Xsb[p * 32 + ((B ^ sw) << 2)] = q4;
      }
    }
  };

  STAGE((unsigned*)u_raw, 0);
  __syncthreads();
#pragma unroll
  for (int c = 0; c < 4; c++) {
    unsigned* Xcur = (unsigned*)(u_raw + ((c & 1) ? 32768 : 0));
    if (c < 3) STAGE((unsigned*)(u_raw + (((c + 1) & 1) ? 32768 : 0)), c + 1);
    H8 bh[4], bl[4];
#pragma unroll
    for (int pt = 0; pt < 4; pt++) {
      int p = wv * 64 + pt * 16 + x;
      int sw = (p >> 2) & 7;
#pragma unroll
      for (int n = 0; n < 4; n++) {
        int k = quad * 8 + n * 2;
        uint2 d = *(const uint2*)&Xcur[p * 32 + (((k >> 2) ^ sw) << 2) + (k & 3)];
        bh[pt].u[n] = __builtin_amdgcn_perm(d.y, d.x, 0x05040100u);
        bl[pt].u[n] = __builtin_amdgcn_perm(d.y, d.x, 0x07060302u);
      }
    }
#pragma unroll
    for (int hh = 0; hh < 8; hh++) {
      int hrow = hh * 16 + x;
      H8 ah, al;
      *(uint4*)&ah.u[0] = *(const uint4*)(Whi + (size_t)hrow * 64 + c * 16 + quad * 4);
      *(uint4*)&al.u[0] = *(const uint4*)(Wlo + (size_t)hrow * 64 + c * 16 + quad * 4);
#pragma unroll
      for (int pt = 0; pt < 4; pt++) {
        acc[pt][hh] = __builtin_amdgcn_mfma_f32_16x16x32_f16(ah.v, bh[pt].v, acc[pt][hh], 0, 0, 0);
        acc[pt][hh] = __builtin_amdgcn_mfma_f32_16x16x32_f16(ah.v, bl[pt].v, acc[pt][hh], 0, 0, 0);
        acc[pt][hh] = __builtin_amdgcn_mfma_f32_16x16x32_f16(al.v, bh[pt].v, acc[pt][hh], 0, 0, 0);
      }
    }
    if (c < 3) __syncthreads();
  }

  // ---- phase B: LN + relu in registers (acc := Y)
  {
    float gm[4], gr[4];
#pragma unroll
    for (int pt = 0; pt < 4; pt++) {
      float s = 0.f;
#pragma unroll
      for (int hh = 0; hh < 8; hh++)
#pragma unroll
        for (int r = 0; r < 4; r++) s += acc[pt][hh][r];
      s += __shfl_xor(s, 16);
      s += __shfl_xor(s, 32);
      float m = s * (1.f / 128.f);
      float qv = 0.f;
#pragma unroll
      for (int hh = 0; hh < 8; hh++)
#pragma unroll
        for (int r = 0; r < 4; r++) { float d = acc[pt][hh][r] - m; qv += d * d; }
      qv += __shfl_xor(qv, 16);
      qv += __shfl_xor(qv, 32);
      gm[pt] = m;
      gr[pt] = rsqrtf(qv * (1.f / 128.f) + 1e-5f);
    }
#pragma unroll
    for (int hh = 0; hh < 8; hh++) {
      float4 g4 = *(const float4*)(gcl + hh * 16 + quad * 4);
      float4 c4 = *(const float4*)(ccl + hh * 16 + quad * 4);
      float ga[4] = {g4.x, g4.y, g4.z, g4.w};
      float ca[4] = {c4.x, c4.y, c4.z, c4.w};
#pragma unroll
      for (int r = 0; r < 4; r++)
#pragma unroll
        for (int pt = 0; pt < 4; pt++)
          acc[pt][hh][r] = fmaxf((acc[pt][hh][r] - gm[pt]) * gr[pt] * ga[r] + ca[r], 0.f);
    }
  }

  // ---- phase C: 4 rounds x 32 planes; msg via MFMA; residual PREFETCH.
  int xi = x & 7;
#pragma unroll
  for (int q = 0; q < 4; q++) {
    __syncthreads();   // Yp region free (Xs reads done / prev round done)
#pragma unroll
    for (int hq = 0; hq < 2; hq++) {
      int hh = q * 2 + hq;
#pragma unroll
      for (int pt = 0; pt < 4; pt++) {
        int qv = pt * 16 + x;
        int ii = wv * 2 + (qv >> 5);
        int kk = qv & 31;
#pragma unroll
        for (int r = 0; r < 4; r++)
          Yp[(hq * 16 + quad * 4 + r) * 268 + ii * 33 + kk] = packf16(acc[pt][hh][r]);
      }
    }
    __syncthreads();
    // prefetch this wave's 16 residual float4s (8 planes x 2 jt): all
    // loads in flight together -> one latency exposure per round.
    float4 xres0[8], xres1[8];
#pragma unroll
    for (int pl = 0; pl < 8; pl++) {
      int h = q * 32 + wv * 8 + pl;
      const float* xrow = Xp + (((size_t)(g * 128 + h)) << 10) + (oct * 8 + xi) * 32;
      xres0[pl] = *(const float4*)(xrow + quad * 4);
      xres1[pl] = *(const float4*)(xrow + 16 + quad * 4);
    }
#pragma unroll
    for (int pl = 0; pl < 8; pl++) {
      int hrel = wv * 8 + pl;
      int h = q * 32 + hrel;
      H8 ybh, ybl;
#pragma unroll
      for (int n = 0; n < 4; n++) {
        uint2 d = *(const uint2*)&Yp[hrel * 268 + x * 33 + quad * 8 + n * 2];
        ybh.u[n] = __builtin_amdgcn_perm(d.y, d.x, 0x05040100u);
        ybl.u[n] = __builtin_amdgcn_perm(d.y, d.x, 0x07060302u);
      }
      float* xrow = Xp + (((size_t)(g * 128 + h)) << 10) + (oct * 8 + xi) * 32;
      float psum = 0.f;
#pragma unroll
      for (int jt = 0; jt < 2; jt++) {
        H8 ah, al;
#pragma unroll
        for (int n = 0; n < 4; n++) {
          unsigned p0 = epk[h * 18 + cod[jt][n][0]];
          unsigned p1 = epk[h * 18 + cod[jt][n][1]];
          ah.u[n] = __builtin_amdgcn_perm(p1, p0, 0x05040100u);
          al.u[n] = __builtin_amdgcn_perm(p1, p0, 0x07060302u);
        }
        float4 xv = jt == 0 ? xres0[pl] : xres1[pl];
        f32x4 cfr; cfr[0] = xv.x; cfr[1] = xv.y; cfr[2] = xv.z; cfr[3] = xv.w;
        cfr = __builtin_amdgcn_mfma_f32_16x16x32_f16(ah.v, ybh.v, cfr, 0, 0, 0);
        cfr = __builtin_amdgcn_mfma_f32_16x16x32_f16(ah.v, ybl.v, cfr, 0, 0, 0);
        cfr = __builtin_amdgcn_mfma_f32_16x16x32_f16(al.v, ybh.v, cfr, 0, 0, 0);
        if (!POOL) {
          if (x < 8) {
            float4 o; o.x = cfr[0]; o.y = cfr[1]; o.z = cfr[2]; o.w = cfr[3];
            *(float4*)(xrow + jt * 16 + quad * 4) = o;
          }
        } else {
          psum += cfr[0] + cfr[1] + cfr[2] + cfr[3];
        }
      }
      if (POOL) {
        psum += __shfl_xor(psum, 16);
        psum += __shfl_xor(psum, 32);
        if (quad == 0 && x < 8)
          Pm[(size_t)g * 4096 + h * 32 + oct * 8 + x] = psum * 0.03125f;
      }
    }
  }
}

// ---------------------------------------------------------------------------
// T v3: reads pooled means from Pm[g][h][i] (written by k_fused<1>).
// ---------------------------------------------------------------------------
__global__ __launch_bounds__(256) void k_tail(
    const float* __restrict__ Pm,
    const float* __restrict__ Wp, const float* __restrict__ bp,
    const float* __restrict__ gp, const float* __restrict__ cp,
    const float* __restrict__ Wq1, const float* __restrict__ bq1,
    const float* __restrict__ gq1, const float* __restrict__ cq1,
    const float* __restrict__ Wq2, const float* __restrict__ bq2,
    float* __restrict__ out) {
  int g = blockIdx.x, tid = threadIdx.x;
  __shared__ float xs_s[32 * 132];
  __shared__ float y_s[32 * 132];
  __shared__ float stat_m[1], stat_r[1];
  __shared__ float hg_s[128];
  __shared__ float q_s[128];
  __shared__ float redf[128];
  const float* Pg = Pm + (size_t)g * 4096;
  {
    int h = tid >> 1, i0 = (tid & 1) * 16;
    const float4* src = (const float4*)(Pg + h * 32 + i0);
    float4 v0 = src[0], v1 = src[1], v2 = src[2], v3 = src[3];
    xs_s[(i0 +  0) * 132 + h] = v0.x; xs_s[(i0 +  1) * 132 + h] = v0.y;
    xs_s[(i0 +  2) * 132 + h] = v0.z; xs_s[(i0 +  3) * 132 + h] = v0.w;
    xs_s[(i0 +  4) * 132 + h] = v1.x; xs_s[(i0 +  5) * 132 + h] = v1.y;
    xs_s[(i0 +  6) * 132 + h] = v1.z; xs_s[(i0 +  7) * 132 + h] = v1.w;
    xs_s[(i0 +  8) * 132 + h] = v2.x; xs_s[(i0 +  9) * 132 + h] = v2.y;
    xs_s[(i0 + 10) * 132 + h] = v2.z; xs_s[(i0 + 11) * 132 + h] = v2.w;
    xs_s[(i0 + 12) * 132 + h] = v3.x; xs_s[(i0 + 13) * 132 + h] = v3.y;
    xs_s[(i0 + 14) * 132 + h] = v3.z; xs_s[(i0 + 15) * 132 + h] = v3.w;
  }
  __syncthreads();
  int i_ = tid >> 3, h0 = (tid & 7) * 16;
  float acc[16];
#pragma unroll
  for (int hh = 0; hh < 16; hh++) acc[hh] = bp[h0 + hh];
  for (int k = 0; k < 128; k++) {
    float a = xs_s[i_ * 132 + k];
    const float4* wr = (const float4*)(Wp + k * 128 + h0);
    float4 w0 = wr[0], w1 = wr[1], w2 = wr[2], w3 = wr[3];
    acc[0]  += a * w0.x; acc[1]  += a * w0.y; acc[2]  += a * w0.z; acc[3]  += a * w0.w;
    acc[4]  += a * w1.x; acc[5]  += a * w1.y; acc[6]  += a * w1.z; acc[7]  += a * w1.w;
    acc[8]  += a * w2.x; acc[9]  += a * w2.y; acc[10] += a * w2.z; acc[11] += a * w2.w;
    acc[12] += a * w3.x; acc[13] += a * w3.y; acc[14] += a * w3.z; acc[15] += a * w3.w;
  }
  {
    float s = 0.f;
#pragma unroll
    for (int hh = 0; hh < 16; hh++) s += acc[hh];
    s += __shfl_xor(s, 1); s += __shfl_xor(s, 2); s += __shfl_xor(s, 4);
    float m = s * (1.f / 128.f);
    float qv = 0.f;
#pragma unroll
    for (int hh = 0; hh < 16; hh++) { float d = acc[hh] - m; qv += d * d; }
    qv += __shfl_xor(qv, 1); qv += __shfl_xor(qv, 2); qv += __shfl_xor(qv, 4);
    float r = rsqrtf(qv * (1.f / 128.f) + 1e-5f);
#pragma unroll
    for (int hh = 0; hh < 16; hh++) {
      int hc = h0 + hh;
      float v = (acc[hh] - m) * r * gp[hc] + cp[hc];
      y_s[i_ * 132 + hc] = fmaxf(v, 0.f);
    }
  }
  __syncthreads();
  if (tid < 128) {
    float s = 0.f;
#pragma unroll
    for (int ii = 0; ii < 32; ii++) s += y_s[ii * 132 + tid];
    hg_s[tid] = s;
  }
  __syncthreads();
  if (tid < 128) {
    float a = bq1[tid];
    for (int k = 0; k < 128; k++) a += hg_s[k] * Wq1[k * 128 + tid];
    q_s[tid] = a;
  }
  __syncthreads();
  if (tid < 64) {
    float a = q_s[tid], b = q_s[tid + 64];
    float s = a + b;
#pragma unroll
    for (int o = 1; o < 64; o <<= 1) s += __shfl_xor(s, o);
    float m = s * (1.f / 128.f);
    float d1 = a - m, d2 = b - m;
    float qq = d1 * d1 + d2 * d2;
#pragma unroll
    for (int o = 1; o < 64; o <<= 1) qq += __shfl_xor(qq, o);
    if (tid == 0) { stat_m[0] = m; stat_r[0] = rsqrtf(qq * (1.f / 128.f) + 1e-5f); }
  }
  __syncthreads();
  if (tid < 128) {
    float v = (q_s[tid] - stat_m[0]) * stat_r[0] * gq1[tid] + cq1[tid];
    v = fmaxf(v, 0.f);
    redf[tid] = v * Wq2[tid];
  }
  __syncthreads();
  if (tid < 64) {
    float s = redf[tid] + redf[tid + 64];
#pragma unroll
    for (int o = 1; o < 64; o <<= 1) s += __shfl_xor(s, o);
    if (tid == 0) out[g] = s + bq2[0];
  }
}

// ---------------------------------------------------------------------------
extern "C" void kernel_launch(void* const* d_in, const int* in_sizes, int n_in,
                              void* d_out, int out_size, void* d_ws, size_t ws_size,
                              hipStream_t stream) {
  const int*   x_idx  = (const int*)d_in[0];
  const int*   ea_idx = (const int*)d_in[1];
  const int*   tf_idx = (const int*)d_in[2];
  const int*   adj    = (const int*)d_in[3];
  const float* emb_x  = (const float*)d_in[4];
  const float* emb_ea = (const float*)d_in[5];
  const float* emb_tf = (const float*)d_in[6];
  const float* W0  = (const float*)d_in[7];
  const float* b0  = (const float*)d_in[8];
  const float* W1  = (const float*)d_in[9];
  const float* b1  = (const float*)d_in[10];
  const float* Wc  = (const float*)d_in[11];
  const float* bc  = (const float*)d_in[12];
  const float* gc  = (const float*)d_in[13];
  const float* cc  = (const float*)d_in[14];
  const float* Wp  = (const float*)d_in[15];
  const float* bp  = (const float*)d_in[16];
  const float* gp  = (const float*)d_in[17];
  const float* cp  = (const float*)d_in[18];
  const float* Wq1 = (const float*)d_in[19];
  const float* bq1 = (const float*)d_in[20];
  const float* gq1 = (const float*)d_in[21];
  const float* cq1 = (const float*)d_in[22];
  const float* Wq2 = (const float*)d_in[23];
  const float* bq2 = (const float*)d_in[24];
  float* out = (float*)d_out;

  float* ws = (float*)d_ws;
  float* Xp = ws;
  float* Pm = ws + (size_t)16777216;
  float* P0 = ws + (size_t)33554432;
  float* P1 = P0 + 4096;
  unsigned* Whi = (unsigned*)(ws + (size_t)33562624);  // 6*128*64 u32
  unsigned* Wlo = Whi + 49152;

  k_emb_mm<<<2, 256, 0, stream>>>(emb_x, W0, b0, P0, W1, b1, P1);
  k_packW<<<192, 256, 0, stream>>>(Wc, Whi, Wlo);
  k_buildX<<<G, 256, 0, stream>>>(x_idx, tf_idx, P0, P1, emb_tf, Xp);
  for (int l = 0; l < L; l++) {
    if (l == L - 1)
      k_fused<1><<<G * 4, 256, 0, stream>>>(Xp, Whi + (size_t)l * 8192,
                                            Wlo + (size_t)l * 8192,
                                            bc + l * H, gc + l * H, cc + l * H,
                                            ea_idx, adj, emb_ea, Pm);
    else
      k_fused<0><<<G * 4, 256, 0, stream>>>(Xp, Whi + (size_t)l * 8192,
                                            Wlo + (size_t)l * 8192,
                                            bc + l * H, gc + l * H, cc + l * H,
                                            ea_idx, adj, emb_ea, Pm);
  }
  k_tail<<<G, 256, 0, stream>>>(Pm, Wp, bp, gp, cp, Wq1, bq1, gq1, cq1, Wq2, bq2, out);
}

// Round 18
// 527.127 us; speedup vs baseline: 1.3323x; 1.2590x over previous
//
#include <hip/hip_runtime.h>

#define G 128
#define N 32
#define H 128
#define L 6

typedef _Float16 half8 __attribute__((ext_vector_type(8)));
typedef float f32x4 __attribute__((ext_vector_type(4)));

union H8 { unsigned u[4]; half8 v; };

__device__ inline unsigned short f16_bits(_Float16 h) {
  union { _Float16 f; unsigned short u; } c; c.f = h; return c.u;
}

// pack fp32 -> (f16 hi) | (f16 lo)<<16, hi = rne(x), lo = rne(x - hi)
__device__ inline unsigned packf16(float x) {
  _Float16 hi = (_Float16)x;
  _Float16 lo = (_Float16)(x - (float)hi);
  return (unsigned)f16_bits(hi) | ((unsigned)f16_bits(lo) << 16);
}

// ---------------------------------------------------------------------------
// HEAD (merged E1 + PW, independent preprocessing; saves one launch):
//  blocks 0-1:   P0 = emb_x @ W0 + b0, P1 = emb_x @ W1 + b1
//  blocks 2-193: pre-pack Wc as f16 hi/lo pair planes (transposed)
// ---------------------------------------------------------------------------
__global__ __launch_bounds__(256) void k_head(
    const float* __restrict__ emb_x,
    const float* __restrict__ W0, const float* __restrict__ b0, float* __restrict__ P0,
    const float* __restrict__ W1, const float* __restrict__ b1, float* __restrict__ P1,
    const float* __restrict__ Wc, unsigned* __restrict__ Whi,
    unsigned* __restrict__ Wlo) {
  int tid = threadIdx.x;
  if (blockIdx.x >= 2) {
    int o  = (blockIdx.x - 2) * 256 + tid;      // 0 .. 49151
    int kp = o & 63;
    int h  = (o >> 6) & 127;
    int l  = o >> 13;
    const float* Wl = Wc + (size_t)l * 16384;
    float a = Wl[(2 * kp) * 128 + h];
    float b = Wl[(2 * kp + 1) * 128 + h];
    unsigned pa = packf16(a), pb = packf16(b);
    Whi[o] = __builtin_amdgcn_perm(pb, pa, 0x05040100u);
    Wlo[o] = __builtin_amdgcn_perm(pb, pa, 0x07060302u);
    return;
  }
  const float* W = blockIdx.x ? W1 : W0;
  const float* b = blockIdx.x ? b1 : b0;
  float*       P = blockIdx.x ? P1 : P0;
  __shared__ float embs_t[128 * 32];   // [k][i]
  {
    int i = tid & 31, k0 = (tid >> 5) * 16;
    const float* src = emb_x + i * 128 + k0;
#pragma unroll
    for (int m = 0; m < 16; m++) embs_t[(k0 + m) * 32 + i] = src[m];
  }
  __syncthreads();
  int i  = tid >> 3;
  int h0 = (tid & 7) * 16;
  float acc[16];
#pragma unroll
  for (int hh = 0; hh < 16; hh++) acc[hh] = b[h0 + hh];
  for (int k = 0; k < 128; k++) {
    float a = embs_t[k * 32 + i];
    const float4* wr = (const float4*)(W + k * 128 + h0);
    float4 w0 = wr[0], w1 = wr[1], w2 = wr[2], w3 = wr[3];
    acc[0]  += a * w0.x; acc[1]  += a * w0.y; acc[2]  += a * w0.z; acc[3]  += a * w0.w;
    acc[4]  += a * w1.x; acc[5]  += a * w1.y; acc[6]  += a * w1.z; acc[7]  += a * w1.w;
    acc[8]  += a * w2.x; acc[9]  += a * w2.y; acc[10] += a * w2.z; acc[11] += a * w2.w;
    acc[12] += a * w3.x; acc[13] += a * w3.y; acc[14] += a * w3.z; acc[15] += a * w3.w;
  }
  float4* dst = (float4*)(P + i * 128 + h0);
  dst[0] = make_float4(acc[0], acc[1], acc[2], acc[3]);
  dst[1] = make_float4(acc[4], acc[5], acc[6], acc[7]);
  dst[2] = make_float4(acc[8], acc[9], acc[10], acc[11]);
  dst[3] = make_float4(acc[12], acc[13], acc[14], acc[15]);
}

// ---------------------------------------------------------------------------
// E2: build X h-planar: Xp[g][h][i*32+j]. One WG per graph.
// ---------------------------------------------------------------------------
__global__ __launch_bounds__(256) void k_buildX(
    const int* __restrict__ x_idx, const int* __restrict__ tf_idx,
    const float* __restrict__ P0, const float* __restrict__ P1,
    const float* __restrict__ emb_tf, float* __restrict__ Xp) {
  int g = blockIdx.x, tid = threadIdx.x;
  __shared__ float x0t[128 * 32];
  __shared__ float x1t[128 * 32];
  __shared__ float etf[128 * 16];
  __shared__ int   tfs[1024];
  {
    int i = tid & 31, h0 = (tid >> 5) * 16;
    int r = x_idx[g * 32 + i];
    const float* s0 = P0 + r * 128 + h0;
    const float* s1 = P1 + r * 128 + h0;
#pragma unroll
    for (int m = 0; m < 16; m++) {
      x0t[(h0 + m) * 32 + i] = s0[m];
      x1t[(h0 + m) * 32 + i] = s1[m];
    }
  }
  {
    int t = tid & 15, h0 = (tid >> 4) * 8;
    const float* s = emb_tf + t * 128 + h0;
#pragma unroll
    for (int m = 0; m < 8; m++) etf[(h0 + m) * 16 + t] = s[m];
  }
  ((int4*)tfs)[tid] = ((const int4*)(tf_idx + (size_t)g * 1024))[tid];
  __syncthreads();
  int i = tid >> 3, j0 = (tid & 7) * 4;
  int t0 = tfs[i * 32 + j0 + 0], t1 = tfs[i * 32 + j0 + 1];
  int t2 = tfs[i * 32 + j0 + 2], t3 = tfs[i * 32 + j0 + 3];
  float* outg = Xp + ((size_t)g << 17);
  for (int h = 0; h < 128; h++) {
    float a = x0t[h * 32 + i];
    const float* x1r = x1t + h * 32;
    const float* er  = etf + h * 16;
    float4 v;
    v.x = a * x1r[j0 + 0] * er[t0];
    v.y = a * x1r[j0 + 1] * er[t1];
    v.z = a * x1r[j0 + 2] * er[t2];
    v.w = a * x1r[j0 + 3] * er[t3];
    *(float4*)(outg + h * 1024 + tid * 4) = v;
  }
}

// ---------------------------------------------------------------------------
// KF v16 (fused conv layer, REVERTED to the round-15 verified kernel:
// 60.0us/dispatch, total 529, absmax 0). v18's register-hungry residual
// prefetch spilled (allocator pins at 128 VGPR; v16 sits at 124) and is
// removed, along with the unisolated cod-hoist/stride-33 tweaks.
//  - phase A: v13 dbuf mlp (f16 hi/lo 3-MFMA, Whi/Wlo direct from L2)
//  - phase B: in-register LN+relu
//  - phase C: 4 rounds x 32 planes, msg via MFMA with pre-packed epk
//    edge table (round-15's verified form: Yp stride 34, c8 in-loop).
// grid G*4, 256 thr, launch_bounds(256,2). LDS 74.2KB -> 2 WGs/CU.
// ---------------------------------------------------------------------------
template <int POOL>
__global__ __launch_bounds__(256, 2) void k_fused(
    float* __restrict__ Xp,
    const unsigned* __restrict__ Whi, const unsigned* __restrict__ Wlo,
    const float* __restrict__ bcl, const float* __restrict__ gcl,
    const float* __restrict__ ccl,
    const int* __restrict__ ea_idx, const int* __restrict__ adj,
    const float* __restrict__ emb_ea, float* __restrict__ Pm) {
  int g = blockIdx.x >> 2, oct = blockIdx.x & 3;
  int tid = threadIdx.x;
  int lane = tid & 63, wv = tid >> 6;
  int x = lane & 15, quad = lane >> 4;

  __shared__ __align__(16) unsigned char u_raw[65536];
  // phase A: Xs[2][8192 words] (double buffer, 32KB each)
  // phase C: Yp packed Y pairs, [32 planes][276 words], rows stride 34
  unsigned* Yp = (unsigned*)u_raw;
  __shared__ unsigned char c8[1024];
  __shared__ unsigned epk[128 * 18];   // packed f16 hi|lo edge values

  // ---- stage A-codes and pre-packed edge table
  {
    int4 ev = ((const int4*)(ea_idx + (size_t)g * 1024))[tid];
    int4 av = ((const int4*)(adj   + (size_t)g * 1024))[tid];
    uchar4 c;
    c.x = av.x ? (unsigned char)ev.x : (unsigned char)16;
    c.y = av.y ? (unsigned char)ev.y : (unsigned char)16;
    c.z = av.z ? (unsigned char)ev.z : (unsigned char)16;
    c.w = av.w ? (unsigned char)ev.w : (unsigned char)16;
    ((uchar4*)c8)[tid] = c;
  }
#pragma unroll
  for (int it = 0; it < 8; it++) {
    int idx = it * 256 + tid;
    int e = idx >> 7, h = idx & 127;
    epk[h * 18 + e] = packf16(emb_ea[e * 128 + h]);
  }
  if (tid < 128) epk[tid * 18 + 16] = 0u;   // packf16(0) == 0

  // ---- phase A: mlp. acc[pt][hh]; p = wv*64+pt*16+x, h = hh*16+quad*4+r
  f32x4 acc[4][8];
#pragma unroll
  for (int hh = 0; hh < 8; hh++) {
    float4 b4 = *(const float4*)(bcl + hh * 16 + quad * 4);
    f32x4 bi; bi[0] = b4.x; bi[1] = b4.y; bi[2] = b4.z; bi[3] = b4.w;
#pragma unroll
    for (int pt = 0; pt < 4; pt++) acc[pt][hh] = bi;
  }
  const float* Xg = Xp + ((size_t)g << 17) + oct * 256;

  auto STAGE = [&](unsigned* Xsb, int c) {
    unsigned pk[8][4];
#pragma unroll
    for (int m = 0; m < 8; m++) {
      float4 v = *(const float4*)(Xg + (size_t)(c * 32 + wv * 8 + m) * 1024 + lane * 4);
      pk[m][0] = packf16(v.x); pk[m][1] = packf16(v.y);
      pk[m][2] = packf16(v.z); pk[m][3] = packf16(v.w);
    }
#pragma unroll
    for (int r = 0; r < 4; r++) {
      int p = 4 * lane + r;
      int sw = (p >> 2) & 7;
#pragma unroll
      for (int B2 = 0; B2 < 2; B2++) {
        int B = wv * 2 + B2;
        uint4 q4;
        q4.x = pk[B2 * 4 + 0][r]; q4.y = pk[B2 * 4 + 1][r];
        q4.z = pk[B2 * 4 + 2][r]; q4.w = pk[B2 * 4 + 3][r];
        *(uint4*)&Xsb[p * 32 + ((B ^ sw) << 2)] = q4;
      }
    }
  };

  STAGE((unsigned*)u_raw, 0);
  __syncthreads();
#pragma unroll
  for (int c = 0; c < 4; c++) {
    unsigned* Xcur = (unsigned*)(u_raw + ((c & 1) ? 32768 : 0));
    if (c < 3) STAGE((unsigned*)(u_raw + (((c + 1) & 1) ? 32768 : 0)), c + 1);
    H8 bh[4], bl[4];
#pragma unroll
    for (int pt = 0; pt < 4; pt++) {
      int p = wv * 64 + pt * 16 + x;
      int sw = (p >> 2) & 7;
#pragma unroll
      for (int n = 0; n < 4; n++) {
        int k = quad * 8 + n * 2;
        uint2 d = *(const uint2*)&Xcur[p * 32 + (((k >> 2) ^ sw) << 2) + (k & 3)];
        bh[pt].u[n] = __builtin_amdgcn_perm(d.y, d.x, 0x05040100u);
        bl[pt].u[n] = __builtin_amdgcn_perm(d.y, d.x, 0x07060302u);
      }
    }
#pragma unroll
    for (int hh = 0; hh < 8; hh++) {
      int hrow = hh * 16 + x;
      H8 ah, al;
      *(uint4*)&ah.u[0] = *(const uint4*)(Whi + (size_t)hrow * 64 + c * 16 + quad * 4);
      *(uint4*)&al.u[0] = *(const uint4*)(Wlo + (size_t)hrow * 64 + c * 16 + quad * 4);
#pragma unroll
      for (int pt = 0; pt < 4; pt++) {
        acc[pt][hh] = __builtin_amdgcn_mfma_f32_16x16x32_f16(ah.v, bh[pt].v, acc[pt][hh], 0, 0, 0);
        acc[pt][hh] = __builtin_amdgcn_mfma_f32_16x16x32_f16(ah.v, bl[pt].v, acc[pt][hh], 0, 0, 0);
        acc[pt][hh] = __builtin_amdgcn_mfma_f32_16x16x32_f16(al.v, bh[pt].v, acc[pt][hh], 0, 0, 0);
      }
    }
    if (c < 3) __syncthreads();
  }

  // ---- phase B: LN + relu in registers (acc := Y)
  {
    float gm[4], gr[4];
#pragma unroll
    for (int pt = 0; pt < 4; pt++) {
      float s = 0.f;
#pragma unroll
      for (int hh = 0; hh < 8; hh++)
#pragma unroll
        for (int r = 0; r < 4; r++) s += acc[pt][hh][r];
      s += __shfl_xor(s, 16);
      s += __shfl_xor(s, 32);
      float m = s * (1.f / 128.f);
      float qv = 0.f;
#pragma unroll
      for (int hh = 0; hh < 8; hh++)
#pragma unroll
        for (int r = 0; r < 4; r++) { float d = acc[pt][hh][r] - m; qv += d * d; }
      qv += __shfl_xor(qv, 16);
      qv += __shfl_xor(qv, 32);
      gm[pt] = m;
      gr[pt] = rsqrtf(qv * (1.f / 128.f) + 1e-5f);
    }
#pragma unroll
    for (int hh = 0; hh < 8; hh++) {
      float4 g4 = *(const float4*)(gcl + hh * 16 + quad * 4);
      float4 c4 = *(const float4*)(ccl + hh * 16 + quad * 4);
      float ga[4] = {g4.x, g4.y, g4.z, g4.w};
      float ca[4] = {c4.x, c4.y, c4.z, c4.w};
#pragma unroll
      for (int r = 0; r < 4; r++)
#pragma unroll
        for (int pt = 0; pt < 4; pt++)
          acc[pt][hh][r] = fmaxf((acc[pt][hh][r] - gm[pt]) * gr[pt] * ga[r] + ca[r], 0.f);
    }
  }

  // ---- phase C: 4 rounds x 32 planes; msg via MFMA.
  int xi = x & 7;
#pragma unroll
  for (int q = 0; q < 4; q++) {
    __syncthreads();   // Yp region free (Xs reads done / prev round done)
#pragma unroll
    for (int hq = 0; hq < 2; hq++) {
      int hh = q * 2 + hq;
#pragma unroll
      for (int pt = 0; pt < 4; pt++) {
        int qv = pt * 16 + x;
        int ii = wv * 2 + (qv >> 5);
        int kk = qv & 31;
#pragma unroll
        for (int r = 0; r < 4; r++)
          Yp[(hq * 16 + quad * 4 + r) * 276 + ii * 34 + kk] = packf16(acc[pt][hh][r]);
      }
    }
    __syncthreads();
#pragma unroll 1
    for (int pl = 0; pl < 8; pl++) {
      int hrel = wv * 8 + pl;
      int h = q * 32 + hrel;
      // B-op (Y) fragments: col i = x, k = quad*8 + n*2 (+1)
      H8 ybh, ybl;
#pragma unroll
      for (int n = 0; n < 4; n++) {
        uint2 d = *(const uint2*)&Yp[hrel * 276 + x * 34 + quad * 8 + n * 2];
        ybh.u[n] = __builtin_amdgcn_perm(d.y, d.x, 0x05040100u);
        ybl.u[n] = __builtin_amdgcn_perm(d.y, d.x, 0x07060302u);
      }
      float* xrow = Xp + (((size_t)(g * 128 + h)) << 10) + (oct * 8 + xi) * 32;
      float psum = 0.f;
#pragma unroll
      for (int jt = 0; jt < 2; jt++) {
        // A-op (edge^T) fragments via pre-packed epk
        H8 ah, al;
#pragma unroll
        for (int n = 0; n < 4; n++) {
          int k = quad * 8 + n * 2;
          unsigned c0 = c8[k * 32 + jt * 16 + x];
          unsigned c1 = c8[(k + 1) * 32 + jt * 16 + x];
          unsigned p0 = epk[h * 18 + c0];
          unsigned p1 = epk[h * 18 + c1];
          ah.u[n] = __builtin_amdgcn_perm(p1, p0, 0x05040100u);
          al.u[n] = __builtin_amdgcn_perm(p1, p0, 0x07060302u);
        }
        float4 xv = *(const float4*)(xrow + jt * 16 + quad * 4);
        f32x4 cfr; cfr[0] = xv.x; cfr[1] = xv.y; cfr[2] = xv.z; cfr[3] = xv.w;
        cfr = __builtin_amdgcn_mfma_f32_16x16x32_f16(ah.v, ybh.v, cfr, 0, 0, 0);
        cfr = __builtin_amdgcn_mfma_f32_16x16x32_f16(ah.v, ybl.v, cfr, 0, 0, 0);
        cfr = __builtin_amdgcn_mfma_f32_16x16x32_f16(al.v, ybh.v, cfr, 0, 0, 0);
        if (!POOL) {
          if (x < 8) {
            float4 o; o.x = cfr[0]; o.y = cfr[1]; o.z = cfr[2]; o.w = cfr[3];
            *(float4*)(xrow + jt * 16 + quad * 4) = o;
          }
        } else {
          psum += cfr[0] + cfr[1] + cfr[2] + cfr[3];
        }
      }
      if (POOL) {
        psum += __shfl_xor(psum, 16);
        psum += __shfl_xor(psum, 32);
        if (quad == 0 && x < 8)
          Pm[(size_t)g * 4096 + h * 32 + oct * 8 + x] = psum * 0.03125f;
      }
    }
  }
}

// ---------------------------------------------------------------------------
// T v3: reads pooled means from Pm[g][h][i] (written by k_fused<1>).
// ---------------------------------------------------------------------------
__global__ __launch_bounds__(256) void k_tail(
    const float* __restrict__ Pm,
    const float* __restrict__ Wp, const float* __restrict__ bp,
    const float* __restrict__ gp, const float* __restrict__ cp,
    const float* __restrict__ Wq1, const float* __restrict__ bq1,
    const float* __restrict__ gq1, const float* __restrict__ cq1,
    const float* __restrict__ Wq2, const float* __restrict__ bq2,
    float* __restrict__ out) {
  int g = blockIdx.x, tid = threadIdx.x;
  __shared__ float xs_s[32 * 132];
  __shared__ float y_s[32 * 132];
  __shared__ float stat_m[1], stat_r[1];
  __shared__ float hg_s[128];
  __shared__ float q_s[128];
  __shared__ float redf[128];
  const float* Pg = Pm + (size_t)g * 4096;
  {
    int h = tid >> 1, i0 = (tid & 1) * 16;
    const float4* src = (const float4*)(Pg + h * 32 + i0);
    float4 v0 = src[0], v1 = src[1], v2 = src[2], v3 = src[3];
    xs_s[(i0 +  0) * 132 + h] = v0.x; xs_s[(i0 +  1) * 132 + h] = v0.y;
    xs_s[(i0 +  2) * 132 + h] = v0.z; xs_s[(i0 +  3) * 132 + h] = v0.w;
    xs_s[(i0 +  4) * 132 + h] = v1.x; xs_s[(i0 +  5) * 132 + h] = v1.y;
    xs_s[(i0 +  6) * 132 + h] = v1.z; xs_s[(i0 +  7) * 132 + h] = v1.w;
    xs_s[(i0 +  8) * 132 + h] = v2.x; xs_s[(i0 +  9) * 132 + h] = v2.y;
    xs_s[(i0 + 10) * 132 + h] = v2.z; xs_s[(i0 + 11) * 132 + h] = v2.w;
    xs_s[(i0 + 12) * 132 + h] = v3.x; xs_s[(i0 + 13) * 132 + h] = v3.y;
    xs_s[(i0 + 14) * 132 + h] = v3.z; xs_s[(i0 + 15) * 132 + h] = v3.w;
  }
  __syncthreads();
  int i_ = tid >> 3, h0 = (tid & 7) * 16;
  float acc[16];
#pragma unroll
  for (int hh = 0; hh < 16; hh++) acc[hh] = bp[h0 + hh];
  for (int k = 0; k < 128; k++) {
    float a = xs_s[i_ * 132 + k];
    const float4* wr = (const float4*)(Wp + k * 128 + h0);
    float4 w0 = wr[0], w1 = wr[1], w2 = wr[2], w3 = wr[3];
    acc[0]  += a * w0.x; acc[1]  += a * w0.y; acc[2]  += a * w0.z; acc[3]  += a * w0.w;
    acc[4]  += a * w1.x; acc[5]  += a * w1.y; acc[6]  += a * w1.z; acc[7]  += a * w1.w;
    acc[8]  += a * w2.x; acc[9]  += a * w2.y; acc[10] += a * w2.z; acc[11] += a * w2.w;
    acc[12] += a * w3.x; acc[13] += a * w3.y; acc[14] += a * w3.z; acc[15] += a * w3.w;
  }
  {
    float s = 0.f;
#pragma unroll
    for (int hh = 0; hh < 16; hh++) s += acc[hh];
    s += __shfl_xor(s, 1); s += __shfl_xor(s, 2); s += __shfl_xor(s, 4);
    float m = s * (1.f / 128.f);
    float qv = 0.f;
#pragma unroll
    for (int hh = 0; hh < 16; hh++) { float d = acc[hh] - m; qv += d * d; }
    qv += __shfl_xor(qv, 1); qv += __shfl_xor(qv, 2); qv += __shfl_xor(qv, 4);
    float r = rsqrtf(qv * (1.f / 128.f) + 1e-5f);
#pragma unroll
    for (int hh = 0; hh < 16; hh++) {
      int hc = h0 + hh;
      float v = (acc[hh] - m) * r * gp[hc] + cp[hc];
      y_s[i_ * 132 + hc] = fmaxf(v, 0.f);
    }
  }
  __syncthreads();
  if (tid < 128) {
    float s = 0.f;
#pragma unroll
    for (int ii = 0; ii < 32; ii++) s += y_s[ii * 132 + tid];
    hg_s[tid] = s;
  }
  __syncthreads();
  if (tid < 128) {
    float a = bq1[tid];
    for (int k = 0; k < 128; k++) a += hg_s[k] * Wq1[k * 128 + tid];
    q_s[tid] = a;
  }
  __syncthreads();
  if (tid < 64) {
    float a = q_s[tid], b = q_s[tid + 64];
    float s = a + b;
#pragma unroll
    for (int o = 1; o < 64; o <<= 1) s += __shfl_xor(s, o);
    float m = s * (1.f / 128.f);
    float d1 = a - m, d2 = b - m;
    float qq = d1 * d1 + d2 * d2;
#pragma unroll
    for (int o = 1; o < 64; o <<= 1) qq += __shfl_xor(qq, o);
    if (tid == 0) { stat_m[0] = m; stat_r[0] = rsqrtf(qq * (1.f / 128.f) + 1e-5f); }
  }
  __syncthreads();
  if (tid < 128) {
    float v = (q_s[tid] - stat_m[0]) * stat_r[0] * gq1[tid] + cq1[tid];
    v = fmaxf(v, 0.f);
    redf[tid] = v * Wq2[tid];
  }
  __syncthreads();
  if (tid < 64) {
    float s = redf[tid] + redf[tid + 64];
#pragma unroll
    for (int o = 1; o < 64; o <<= 1) s += __shfl_xor(s, o);
    if (tid == 0) out[g] = s + bq2[0];
  }
}

// ---------------------------------------------------------------------------
extern "C" void kernel_launch(void* const* d_in, const int* in_sizes, int n_in,
                              void* d_out, int out_size, void* d_ws, size_t ws_size,
                              hipStream_t stream) {
  const int*   x_idx  = (const int*)d_in[0];
  const int*   ea_idx = (const int*)d_in[1];
  const int*   tf_idx = (const int*)d_in[2];
  const int*   adj    = (const int*)d_in[3];
  const float* emb_x  = (const float*)d_in[4];
  const float* emb_ea = (const float*)d_in[5];
  const float* emb_tf = (const float*)d_in[6];
  const float* W0  = (const float*)d_in[7];
  const float* b0  = (const float*)d_in[8];
  const float* W1  = (const float*)d_in[9];
  const float* b1  = (const float*)d_in[10];
  const float* Wc  = (const float*)d_in[11];
  const float* bc  = (const float*)d_in[12];
  const float* gc  = (const float*)d_in[13];
  const float* cc  = (const float*)d_in[14];
  const float* Wp  = (const float*)d_in[15];
  const float* bp  = (const float*)d_in[16];
  const float* gp  = (const float*)d_in[17];
  const float* cp  = (const float*)d_in[18];
  const float* Wq1 = (const float*)d_in[19];
  const float* bq1 = (const float*)d_in[20];
  const float* gq1 = (const float*)d_in[21];
  const float* cq1 = (const float*)d_in[22];
  const float* Wq2 = (const float*)d_in[23];
  const float* bq2 = (const float*)d_in[24];
  float* out = (float*)d_out;

  float* ws = (float*)d_ws;
  float* Xp = ws;
  float* Pm = ws + (size_t)16777216;
  float* P0 = ws + (size_t)33554432;
  float* P1 = P0 + 4096;
  unsigned* Whi = (unsigned*)(ws + (size_t)33562624);  // 6*128*64 u32
  unsigned* Wlo = Whi + 49152;

  k_head<<<194, 256, 0, stream>>>(emb_x, W0, b0, P0, W1, b1, P1, Wc, Whi, Wlo);
  k_buildX<<<G, 256, 0, stream>>>(x_idx, tf_idx, P0, P1, emb_tf, Xp);
  for (int l = 0; l < L; l++) {
    if (l == L - 1)
      k_fused<1><<<G * 4, 256, 0, stream>>>(Xp, Whi + (size_t)l * 8192,
                                            Wlo + (size_t)l * 8192,
                                            bc + l * H, gc + l * H, cc + l * H,
                                            ea_idx, adj, emb_ea, Pm);
    else
      k_fused<0><<<G * 4, 256, 0, stream>>>(Xp, Whi + (size_t)l * 8192,
                                            Wlo + (size_t)l * 8192,
                                            bc + l * H, gc + l * H, cc + l * H,
                                            ea_idx, adj, emb_ea, Pm);
  }
  k_tail<<<G, 256, 0, stream>>>(Pm, Wp, bp, gp, cp, Wq1, bq1, gq1, cq1, Wq2, bq2, out);
}